// Round 5
// baseline (176.079 us; speedup 1.0000x reference)
//
#include <hip/hip_runtime.h>
#include <math.h>

// Problem constants (from reference setup_inputs)
#define BB 16
#define CC 85
#define HH 128
#define WW 128
#define NGT 64
#define HW (HH * WW)          // 16384
#define NC (CC - 5)           // 80
#define NCH 81                // channels 4..84 (obj + 80 cls)
#define NPART (BB * NCH)      // 1296 dense partial sums
#define NGTBLK BB             // 16 GT blocks (one per batch)
#define NWORK (NGTBLK + NPART) // 1312 worker blocks; block NWORK is the reducer
#define SIG 0x5F3759DF        // flag signature; != 0xAAAAAAAA poison, != 0

// ws layout (4-byte units):
//   [0 .. NPART)                 dense per-slice softplus sums (slot = b*81 + (c-4))
//   [NPART + 0*BB .. +1*BB)      per-batch box-loss partials
//   [NPART + 1*BB .. +2*BB)      per-batch gathered-obj partials (to subtract)
//   [NPART + 2*BB .. +3*BB)      per-batch gathered-cls partials (to subtract)
//   [FLAG_OFF .. FLAG_OFF+NWORK) int flags, SIG when the block's partial is published
#define GT_OFF  NPART
#define FLAG_OFF (NPART + 3 * BB)

// Device-scope (cross-XCD-coherent) accessors. Partials are published with
// relaxed agent atomics + a release flag; consumed with acquire flag + relaxed
// agent loads — per-XCD L2 non-coherence is handled by the agent scope.
__device__ __forceinline__ void st_flag(int* p, int v) {
    __hip_atomic_store(p, v, __ATOMIC_RELEASE, __HIP_MEMORY_SCOPE_AGENT);
}
__device__ __forceinline__ int ld_flag(const int* p) {
    return __hip_atomic_load(p, __ATOMIC_ACQUIRE, __HIP_MEMORY_SCOPE_AGENT);
}
__device__ __forceinline__ void st_part(float* p, float v) {
    __hip_atomic_store(p, v, __ATOMIC_RELAXED, __HIP_MEMORY_SCOPE_AGENT);
}
__device__ __forceinline__ float ld_part(const float* p) {
    return __hip_atomic_load(p, __ATOMIC_RELAXED, __HIP_MEMORY_SCOPE_AGENT);
}

__device__ __forceinline__ float softplus_f(float x) {
    // logaddexp(x,0) = max(x,0) + log1p(exp(-|x|)); exp(-|x|) in (0,1] so no
    // cancellation; ~1e-7 rel error, and the final means divide by 16384 / 1.3M.
    float ax = fabsf(x);
    float e = __expf(-ax);
    return fmaxf(x, 0.0f) + __logf(1.0f + e);
}

// Single fused kernel, grid = NWORK + 1 blocks x 256 threads (all co-resident:
// 12 VGPR / <1 KB LDS -> ~8 blocks/CU capacity = 2048 >> 1313).
//   blocks [0, 16)        : GT gather + IoU + set-dedup (first so their scattered
//                           loads issue at dispatch start and hide under streaming)
//   blocks [16, 1312)     : dense softplus sum over one (b, c) channel slice
//   block  1312           : spin-wait on flags, final combine, write out
__global__ __launch_bounds__(256) void fused_all(const float* __restrict__ preds,
                                                 const float* __restrict__ tgt,
                                                 float* __restrict__ ws,
                                                 float* __restrict__ out) {
    int* flags = (int*)(ws + FLAG_OFF);
    const int bk = blockIdx.x;

    if (bk < NGTBLK) {
        // ---- GT path: batch b = bk, one GT per lane of wave 0 ----
        const int b = bk;
        const int n = threadIdx.x;
        __shared__ int s_idx[NGT];
        __shared__ int s_cls[NGT];

        float box = 0.0f, sub_o = 0.0f, sub_c = 0.0f;
        int idx = 0, cls = 0;
        float px = 0, py = 0, pw = 0, ph = 0, pobj = 0, pcls = 0;
        float cx = 0, cy = 0, w = 0, h = 0;

        if (n < NGT) {
            const float* t = tgt + ((size_t)(b * NGT + n)) * 5;
            cls = (int)t[0];
            cx = t[1]; cy = t[2]; w = t[3]; h = t[4];
            const int gi = (int)(cx * (float)WW);
            const int gj = (int)(cy * (float)HH);
            idx = gj * WW + gi;
            s_idx[n] = idx;
            s_cls[n] = cls;
            // scattered gathers issued early; latency overlaps dedup
            const float* pb = preds + (size_t)b * CC * HW + idx;
            px   = pb[0 * HW];
            py   = pb[1 * HW];
            pw   = pb[2 * HW];
            ph   = pb[3 * HW];
            pobj = pb[4 * HW];
            pcls = pb[(5 + cls) * HW];
        }
        __syncthreads();

        if (n < NGT) {
            // boxes exactly as the reference computes them
            const float p0 = px - pw * 0.5f, p1 = py - ph * 0.5f;
            const float p2 = px + pw * 0.5f, p3 = py + ph * 0.5f;
            const float g0 = (cx - w * 0.5f) * WW, g1 = (cy - h * 0.5f) * HH;
            const float g2 = (cx + w * 0.5f) * WW, g3 = (cy + h * 0.5f) * HH;

            const float ix1 = fmaxf(p0, g0), iy1 = fmaxf(p1, g1);
            const float ix2 = fminf(p2, g2), iy2 = fminf(p3, g3);
            const float inter = fmaxf(ix2 - ix1, 0.0f) * fmaxf(iy2 - iy1, 0.0f);
            const float a1 = (p2 - p0) * (p3 - p1);
            const float a2 = (g2 - g0) * (g3 - g1);
            const float iou = inter / (a1 + a2 - inter + 1e-7f);
            box = 1.0f - iou;

            // set semantics: a cell counts once (obj); a (cell,cls) pair once (cls)
            bool dup_o = false, dup_c = false;
            for (int m = 0; m < n; ++m) {
                if (s_idx[m] == idx) {
                    dup_o = true;
                    if (s_cls[m] == cls) dup_c = true;
                }
            }
            sub_o = dup_o ? 0.0f : pobj;
            sub_c = dup_c ? 0.0f : pcls;

            #pragma unroll
            for (int off = 32; off > 0; off >>= 1) {
                box   += __shfl_down(box,   off, 64);
                sub_o += __shfl_down(sub_o, off, 64);
                sub_c += __shfl_down(sub_c, off, 64);
            }
            if (n == 0) {
                st_part(&ws[GT_OFF + 0 * BB + b], box);
                st_part(&ws[GT_OFF + 1 * BB + b], sub_o);
                st_part(&ws[GT_OFF + 2 * BB + b], sub_c);
                st_flag(&flags[bk], SIG);
            }
        }
    } else if (bk < NWORK) {
        // ---- dense path: slice = bk-16 -> (b, c); 16384 elems = 256 thr x 16 float4
        const int slice = bk - NGTBLK;
        const int b = slice / NCH;
        const int c = 4 + (slice - b * NCH);
        const float4* p = (const float4*)(preds + ((size_t)(b * CC + c) * HW));

        float s = 0.0f;
        #pragma unroll
        for (int k = 0; k < 16; ++k) {
            float4 v = p[threadIdx.x + (k << 8)];
            s += softplus_f(v.x) + softplus_f(v.y) + softplus_f(v.z) + softplus_f(v.w);
        }

        #pragma unroll
        for (int off = 32; off > 0; off >>= 1) s += __shfl_down(s, off, 64);

        __shared__ float wsum[4];
        const int lane = threadIdx.x & 63;
        const int wv = threadIdx.x >> 6;
        if (lane == 0) wsum[wv] = s;
        __syncthreads();
        if (threadIdx.x == 0) {
            st_part(&ws[slice], wsum[0] + wsum[1] + wsum[2] + wsum[3]);
            st_flag(&flags[bk], SIG);
        }
    } else {
        // ---- reducer: spin on flags, combine, write scalar ----
        const int tid = threadIdx.x;

        // dense partials: thread tid owns slices tid, tid+256, ... and waits on
        // exactly the flags guarding them (no cross-thread visibility games)
        double obj = 0.0, cls = 0.0;
        for (int sidx = tid; sidx < NPART; sidx += 256) {
            while (ld_flag(&flags[NGTBLK + sidx]) != SIG) __builtin_amdgcn_s_sleep(2);
            double v = (double)ld_part(&ws[sidx]);
            if (sidx % NCH == 0) obj += v; else cls += v;   // c==4 slots are obj
        }
        float box = 0.0f, sub_o = 0.0f, sub_c = 0.0f;
        if (tid < BB) {
            while (ld_flag(&flags[tid]) != SIG) __builtin_amdgcn_s_sleep(2);
            box   = ld_part(&ws[GT_OFF + 0 * BB + tid]);
            sub_o = ld_part(&ws[GT_OFF + 1 * BB + tid]);
            sub_c = ld_part(&ws[GT_OFF + 2 * BB + tid]);
        }

        __shared__ double so[256], sc[256];
        __shared__ float sb[256], sso[256], ssc[256];
        so[tid] = obj; sc[tid] = cls; sb[tid] = box; sso[tid] = sub_o; ssc[tid] = sub_c;
        __syncthreads();
        for (int s = 128; s > 0; s >>= 1) {
            if (tid < s) {
                so[tid] += so[tid + s];
                sc[tid] += sc[tid + s];
                sb[tid] += sb[tid + s];
                sso[tid] += sso[tid + s];
                ssc[tid] += ssc[tid + s];
            }
            __syncthreads();
        }
        if (tid == 0) {
            double o = (so[0] - (double)sso[0]) / (double)HW;
            double c = (sc[0] - (double)ssc[0]) / ((double)HW * (double)NC);
            out[0] = (float)(0.05 * (double)sb[0] + 1.0 * o + 0.5 * c);
        }
    }
}

extern "C" void kernel_launch(void* const* d_in, const int* in_sizes, int n_in,
                              void* d_out, int out_size, void* d_ws, size_t ws_size,
                              hipStream_t stream) {
    const float* preds = (const float*)d_in[0];
    const float* targets = (const float*)d_in[1];
    float* out = (float*)d_out;
    float* ws = (float*)d_ws;

    fused_all<<<NWORK + 1, 256, 0, stream>>>(preds, targets, ws, out);
}

// Round 6
// 134.995 us; speedup vs baseline: 1.3043x; 1.3043x over previous
//
#include <hip/hip_runtime.h>
#include <math.h>

// Problem constants (from reference setup_inputs)
#define BB 16
#define CC 85
#define HH 128
#define WW 128
#define NGT 64
#define HW (HH * WW)          // 16384
#define NC (CC - 5)           // 80
#define NCH 81                // channels 4..84 (obj + 80 cls)
#define NPART (BB * NCH)      // 1296 dense partial sums
#define NGTBLK BB             // 16 GT blocks, placed FIRST in the grid

// ws layout (floats):
//   [0 .. NPART)                : dense per-slice softplus sums (slot = b*81 + (c-4))
//   [NPART + 0*BB .. +1*BB)     : per-batch box-loss partials
//   [NPART + 1*BB .. +2*BB)     : per-batch gathered-obj partials (to subtract)
//   [NPART + 2*BB .. +3*BB)     : per-batch gathered-cls partials (to subtract)
#define GT_OFF NPART

__device__ __forceinline__ float softplus_f(float x) {
    // logaddexp(x,0) = max(x,0) + log1p(exp(-|x|)); exp(-|x|) in (0,1] so no
    // cancellation; ~1e-7 rel error, and the final means divide by 16384 / 1.3M.
    float ax = fabsf(x);
    float e = __expf(-ax);
    return fmaxf(x, 0.0f) + __logf(1.0f + e);
}

// Fused worker kernel. Grid: NGTBLK + NPART blocks x 256 threads.
//   blocks [0, 16)   : GT gather + IoU + set-dedup for one batch — FIRST, so the
//                      scattered (one-cacheline) gathers issue at dispatch start
//                      and their latency hides under the dense streaming.
//   blocks [16, ...) : dense softplus sum over one (b, c) channel slice.
// Plain stores to distinct ws slots; no atomics, no device-scope coherence
// traffic (R5 showed agent-scope publish/subscribe craters streaming BW).
__global__ __launch_bounds__(256) void fused_kernel(const float* __restrict__ preds,
                                                    const float* __restrict__ tgt,
                                                    float* __restrict__ ws) {
    const int bk = blockIdx.x;
    if (bk >= NGTBLK) {
        // ---- dense path: slice = bk-16 -> (b, c); 16384 elems = 256 thr x 16 float4
        const int slice = bk - NGTBLK;
        const int b = slice / NCH;
        const int c = 4 + (slice - b * NCH);
        const float4* p = (const float4*)(preds + ((size_t)(b * CC + c) * HW));

        float s = 0.0f;
        #pragma unroll
        for (int k = 0; k < 16; ++k) {
            float4 v = p[threadIdx.x + (k << 8)];
            s += softplus_f(v.x) + softplus_f(v.y) + softplus_f(v.z) + softplus_f(v.w);
        }

        #pragma unroll
        for (int off = 32; off > 0; off >>= 1) s += __shfl_down(s, off, 64);

        __shared__ float wsum[4];
        const int lane = threadIdx.x & 63;
        const int wv = threadIdx.x >> 6;
        if (lane == 0) wsum[wv] = s;
        __syncthreads();
        if (threadIdx.x == 0) ws[slice] = wsum[0] + wsum[1] + wsum[2] + wsum[3];
    } else {
        // ---- GT path: batch b = bk, one GT per lane of wave 0 ----
        const int b = bk;
        const int n = threadIdx.x;
        __shared__ int s_idx[NGT];
        __shared__ int s_cls[NGT];

        float box = 0.0f, sub_o = 0.0f, sub_c = 0.0f;
        int idx = 0, cls = 0;
        float px = 0, py = 0, pw = 0, ph = 0, pobj = 0, pcls = 0;
        float cx = 0, cy = 0, w = 0, h = 0;

        if (n < NGT) {
            const float* t = tgt + ((size_t)(b * NGT + n)) * 5;
            cls = (int)t[0];
            cx = t[1]; cy = t[2]; w = t[3]; h = t[4];
            const int gi = (int)(cx * (float)WW);
            const int gj = (int)(cy * (float)HH);
            idx = gj * WW + gi;
            s_idx[n] = idx;
            s_cls[n] = cls;
            // scattered gathers issued early; latency overlaps the dedup barrier
            const float* pb = preds + (size_t)b * CC * HW + idx;
            px   = pb[0 * HW];
            py   = pb[1 * HW];
            pw   = pb[2 * HW];
            ph   = pb[3 * HW];
            pobj = pb[4 * HW];
            pcls = pb[(5 + cls) * HW];
        }
        __syncthreads();

        if (n < NGT) {
            // boxes exactly as the reference computes them
            const float p0 = px - pw * 0.5f, p1 = py - ph * 0.5f;
            const float p2 = px + pw * 0.5f, p3 = py + ph * 0.5f;
            const float g0 = (cx - w * 0.5f) * WW, g1 = (cy - h * 0.5f) * HH;
            const float g2 = (cx + w * 0.5f) * WW, g3 = (cy + h * 0.5f) * HH;

            const float ix1 = fmaxf(p0, g0), iy1 = fmaxf(p1, g1);
            const float ix2 = fminf(p2, g2), iy2 = fminf(p3, g3);
            const float inter = fmaxf(ix2 - ix1, 0.0f) * fmaxf(iy2 - iy1, 0.0f);
            const float a1 = (p2 - p0) * (p3 - p1);
            const float a2 = (g2 - g0) * (g3 - g1);
            const float iou = inter / (a1 + a2 - inter + 1e-7f);
            box = 1.0f - iou;

            // set semantics: a cell counts once (obj); a (cell,cls) pair once (cls)
            bool dup_o = false, dup_c = false;
            for (int m = 0; m < n; ++m) {
                if (s_idx[m] == idx) {
                    dup_o = true;
                    if (s_cls[m] == cls) dup_c = true;
                }
            }
            sub_o = dup_o ? 0.0f : pobj;
            sub_c = dup_c ? 0.0f : pcls;

            #pragma unroll
            for (int off = 32; off > 0; off >>= 1) {
                box   += __shfl_down(box,   off, 64);
                sub_o += __shfl_down(sub_o, off, 64);
                sub_c += __shfl_down(sub_c, off, 64);
            }
            if (n == 0) {
                ws[GT_OFF + 0 * BB + b] = box;
                ws[GT_OFF + 1 * BB + b] = sub_o;
                ws[GT_OFF + 2 * BB + b] = sub_c;
            }
        }
    }
}

// Final reduce: 1 block x 256 threads over 1296 dense partials + 48 GT partials.
__global__ __launch_bounds__(256) void reduce_kernel(const float* __restrict__ ws,
                                                     float* __restrict__ out) {
    const int tid = threadIdx.x;
    double obj = 0.0, cls = 0.0;
    for (int k = tid; k < NPART; k += 256) {
        double v = (double)ws[k];
        if (k % NCH == 0) obj += v; else cls += v;   // c==4 slots are obj
    }
    float box = 0.0f, sub_o = 0.0f, sub_c = 0.0f;
    if (tid < BB) {
        box   = ws[GT_OFF + 0 * BB + tid];
        sub_o = ws[GT_OFF + 1 * BB + tid];
        sub_c = ws[GT_OFF + 2 * BB + tid];
    }

    __shared__ double so[256], sc[256];
    __shared__ float sb[256], sso[256], ssc[256];
    so[tid] = obj; sc[tid] = cls; sb[tid] = box; sso[tid] = sub_o; ssc[tid] = sub_c;
    __syncthreads();
    for (int s = 128; s > 0; s >>= 1) {
        if (tid < s) {
            so[tid] += so[tid + s];
            sc[tid] += sc[tid + s];
            sb[tid] += sb[tid + s];
            sso[tid] += sso[tid + s];
            ssc[tid] += ssc[tid + s];
        }
        __syncthreads();
    }
    if (tid == 0) {
        double o = (so[0] - (double)sso[0]) / (double)HW;
        double c = (sc[0] - (double)ssc[0]) / ((double)HW * (double)NC);
        out[0] = (float)(0.05 * (double)sb[0] + 1.0 * o + 0.5 * c);
    }
}

extern "C" void kernel_launch(void* const* d_in, const int* in_sizes, int n_in,
                              void* d_out, int out_size, void* d_ws, size_t ws_size,
                              hipStream_t stream) {
    const float* preds = (const float*)d_in[0];
    const float* targets = (const float*)d_in[1];
    float* out = (float*)d_out;
    float* ws = (float*)d_ws;

    fused_kernel<<<NGTBLK + NPART, 256, 0, stream>>>(preds, targets, ws);
    reduce_kernel<<<1, 256, 0, stream>>>(ws, out);
}